// Round 1
// baseline (8275.871 us; speedup 1.0000x reference)
//
#include <hip/hip_runtime.h>
#include <math.h>

#define S_LEN 400
#define BATCH 32
#define HID   512
#define G3    1536
#define VOC   50000
#define OUTW  (VOC + S_LEN)

__device__ __forceinline__ float sigf(float x) { return 1.f / (1.f + expf(-x)); }

// ---------------------------------------------------------------------------
// Persistent bidirectional GRU scan.
// grid = 256 blocks x 256 threads. group = bid&7 (dir = group>>2, bg = group&3),
// ht = bid>>3 (16 hidden units per block). Each group of 32 blocks owns
// (dir, 8 batches) and barriers independently each step.
// ---------------------------------------------------------------------------
__global__ __launch_bounds__(256) void gru_scan(
    const float* __restrict__ xz_fw, const float* __restrict__ xz_bw,
    const float* __restrict__ Ufw, const float* __restrict__ Ubw,
    const float* __restrict__ bfw, const float* __restrict__ bbw,
    float* __restrict__ enc_seq, float* __restrict__ hbuf,
    unsigned* __restrict__ counters)
{
  const int bid = blockIdx.x;
  const int group = bid & 7;
  const int dir = group >> 2;
  const int bg  = group & 3;
  const int ht  = bid >> 3;
  const int tid = threadIdx.x;
  const int jl = tid & 15;
  const int kc = tid >> 4;
  const int k0 = kc * 32;
  const int jg = ht * 16 + jl;

  const float* __restrict__ xz = dir ? xz_bw : xz_fw;
  const float* __restrict__ U  = dir ? Ubw  : Ufw;
  const float* __restrict__ br = (dir ? bbw : bfw) + G3;   // bias row 1
  unsigned* ctr = counters + group * 64;
  float* hb = hbuf + (size_t)dir * (2 * BATCH * HID);

  // U tile in registers: u[g][i] = U[k0+i][g*512 + jg]
  float u0[32], u1[32], u2[32];
  #pragma unroll
  for (int i = 0; i < 32; ++i) {
    const float* up = U + (size_t)(k0 + i) * G3 + jg;
    u0[i] = up[0]; u1[i] = up[512]; u2[i] = up[1024];
  }

  __shared__ float h_lds[8][HID];        // 16 KB
  __shared__ float red[8][3][16][4];     // 6 KB (b, gate, j, wave)

  // gate-phase mapping (threads 0..127)
  const int gbi = tid >> 4;
  const int gj  = tid & 15;
  const int gjq = ht * 16 + gj;
  const int gb  = bg * 8 + gbi;
  const float brz = br[gjq], brr = br[512 + gjq], brh = br[1024 + gjq];

  // zero h0 (buffer 0) for our owned slice
  if (tid < 128) hb[(size_t)gb * HID + gjq] = 0.f;

  // ---- group barrier, phase 1 ----
  __syncthreads();
  if (tid == 0) {
    __threadfence();
    __hip_atomic_fetch_add(ctr, 1u, __ATOMIC_RELEASE, __HIP_MEMORY_SCOPE_AGENT);
    while (__hip_atomic_load(ctr, __ATOMIC_ACQUIRE, __HIP_MEMORY_SCOPE_AGENT) < 32u)
      __builtin_amdgcn_s_sleep(1);
    __threadfence();
  }
  __syncthreads();

  for (int t = 0; t < S_LEN; ++t) {
    const int buf = t & 1;
    // load h (8 batches x 512) into LDS
    {
      const float4* src = (const float4*)(hb + (size_t)buf * BATCH * HID + (size_t)(bg * 8) * HID);
      float4* dst = (float4*)&h_lds[0][0];
      #pragma unroll
      for (int i = 0; i < 4; ++i) dst[tid + 256 * i] = src[tid + 256 * i];
    }
    __syncthreads();

    const int ts = dir ? (S_LEN - 1 - t) : t;
    float xzv0 = 0.f, xzv1 = 0.f, xzv2 = 0.f;
    if (tid < 128) {   // prefetch xz early to hide HBM latency under the FMAs
      const float* xp = xz + ((size_t)gb * S_LEN + ts) * G3 + gjq;
      xzv0 = xp[0]; xzv1 = xp[512]; xzv2 = xp[1024];
    }

    for (int b = 0; b < 8; ++b) {
      float a0 = 0.f, a1 = 0.f, a2 = 0.f;
      const float4* hp = (const float4*)&h_lds[b][k0];
      #pragma unroll
      for (int q = 0; q < 8; ++q) {
        const float4 hv = hp[q];
        a0 += hv.x * u0[4*q+0]; a1 += hv.x * u1[4*q+0]; a2 += hv.x * u2[4*q+0];
        a0 += hv.y * u0[4*q+1]; a1 += hv.y * u1[4*q+1]; a2 += hv.y * u2[4*q+1];
        a0 += hv.z * u0[4*q+2]; a1 += hv.z * u1[4*q+2]; a2 += hv.z * u2[4*q+2];
        a0 += hv.w * u0[4*q+3]; a1 += hv.w * u1[4*q+3]; a2 += hv.w * u2[4*q+3];
      }
      // reduce the 4 k-chunks that live in this wave (lanes xor 16, 32)
      a0 += __shfl_xor(a0, 16); a0 += __shfl_xor(a0, 32);
      a1 += __shfl_xor(a1, 16); a1 += __shfl_xor(a1, 32);
      a2 += __shfl_xor(a2, 16); a2 += __shfl_xor(a2, 32);
      if ((kc & 3) == 0) {
        const int w = kc >> 2;
        red[b][0][jl][w] = a0;
        red[b][1][jl][w] = a1;
        red[b][2][jl][w] = a2;
      }
    }
    __syncthreads();

    if (tid < 128) {
      const float rz = red[gbi][0][gj][0]+red[gbi][0][gj][1]+red[gbi][0][gj][2]+red[gbi][0][gj][3] + brz;
      const float rr = red[gbi][1][gj][0]+red[gbi][1][gj][1]+red[gbi][1][gj][2]+red[gbi][1][gj][3] + brr;
      const float rh = red[gbi][2][gj][0]+red[gbi][2][gj][1]+red[gbi][2][gj][2]+red[gbi][2][gj][3] + brh;
      const float z  = sigf(xzv0 + rz);
      const float r  = sigf(xzv1 + rr);
      const float hh = tanhf(xzv2 + r * rh);
      const float hold = h_lds[gbi][gjq];
      const float hnew = z * hold + (1.f - z) * hh;
      hb[(size_t)(buf ^ 1) * BATCH * HID + (size_t)gb * HID + gjq] = hnew;
      enc_seq[((size_t)gb * S_LEN + ts) * 1024 + dir * 512 + gjq] = hnew;
    }

    // ---- group barrier, phase t+2 ----
    __syncthreads();
    if (tid == 0) {
      __threadfence();
      __hip_atomic_fetch_add(ctr, 1u, __ATOMIC_RELEASE, __HIP_MEMORY_SCOPE_AGENT);
      const unsigned target = 32u * (unsigned)(t + 2);
      while (__hip_atomic_load(ctr, __ATOMIC_ACQUIRE, __HIP_MEMORY_SCOPE_AGENT) < target)
        __builtin_amdgcn_s_sleep(1);
      __threadfence();
    }
    __syncthreads();
  }
}

// ---------------------------------------------------------------------------
// fp32 tiled GEMM, 128x128x16, 256 thr, 8x8 microtile.
// gather: A row = emb[rowids[r]] (embedding gather fused).
// epi_att: fused tanh(acc + dterm) * att_V row-reduction -> e_part.
// ---------------------------------------------------------------------------
__global__ __launch_bounds__(256) void gemm_big(
    const int gather, const int epi_att,
    const int* __restrict__ rowids,
    const float* __restrict__ Abase, const int lda,
    const float* __restrict__ W, const int N, const int K,
    const float* __restrict__ bias,
    float* __restrict__ out,
    const float* __restrict__ dterm, const float* __restrict__ attV,
    float* __restrict__ e_part)
{
  const int m0 = blockIdx.y * 128, n0 = blockIdx.x * 128;
  const int tid = threadIdx.x;
  __shared__ float As[16][128];
  __shared__ float Bs[16][128];
  __shared__ int   rid[128];
  __shared__ float pr[128][16];
  if (tid < 128) rid[tid] = gather ? rowids[m0 + tid] : (m0 + tid);
  __syncthreads();
  float acc[8][8];
  #pragma unroll
  for (int i = 0; i < 8; ++i)
    #pragma unroll
    for (int j = 0; j < 8; ++j) acc[i][j] = 0.f;
  const int tx = tid & 15, ty = tid >> 4;
  const int ar = tid >> 1, ac = (tid & 1) * 8;
  const int bc = tid >> 4, bn = (tid & 15) * 8;

  for (int k0 = 0; k0 < K; k0 += 16) {
    const float* ap = Abase + (size_t)rid[ar] * lda + k0 + ac;
    const float4 av0 = *(const float4*)ap;
    const float4 av1 = *(const float4*)(ap + 4);
    const float* bp = W + (size_t)(k0 + bc) * N + n0 + bn;
    const float4 bv0 = *(const float4*)bp;
    const float4 bv1 = *(const float4*)(bp + 4);
    As[ac+0][ar] = av0.x; As[ac+1][ar] = av0.y; As[ac+2][ar] = av0.z; As[ac+3][ar] = av0.w;
    As[ac+4][ar] = av1.x; As[ac+5][ar] = av1.y; As[ac+6][ar] = av1.z; As[ac+7][ar] = av1.w;
    *(float4*)&Bs[bc][bn]   = bv0;
    *(float4*)&Bs[bc][bn+4] = bv1;
    __syncthreads();
    #pragma unroll
    for (int kk = 0; kk < 16; ++kk) {
      const float4 a0 = *(const float4*)&As[kk][ty*8];
      const float4 a1 = *(const float4*)&As[kk][ty*8+4];
      const float4 b0 = *(const float4*)&Bs[kk][tx*8];
      const float4 b1 = *(const float4*)&Bs[kk][tx*8+4];
      const float a[8]  = {a0.x,a0.y,a0.z,a0.w,a1.x,a1.y,a1.z,a1.w};
      const float bb[8] = {b0.x,b0.y,b0.z,b0.w,b1.x,b1.y,b1.z,b1.w};
      #pragma unroll
      for (int i = 0; i < 8; ++i)
        #pragma unroll
        for (int j = 0; j < 8; ++j)
          acc[i][j] += a[i] * bb[j];
    }
    __syncthreads();
  }

  if (!epi_att) {
    #pragma unroll
    for (int i = 0; i < 8; ++i) {
      const int r = m0 + ty*8 + i;
      float4 o0, o1;
      o0.x = acc[i][0] + bias[n0+tx*8+0];
      o0.y = acc[i][1] + bias[n0+tx*8+1];
      o0.z = acc[i][2] + bias[n0+tx*8+2];
      o0.w = acc[i][3] + bias[n0+tx*8+3];
      o1.x = acc[i][4] + bias[n0+tx*8+4];
      o1.y = acc[i][5] + bias[n0+tx*8+5];
      o1.z = acc[i][6] + bias[n0+tx*8+6];
      o1.w = acc[i][7] + bias[n0+tx*8+7];
      *(float4*)&out[(size_t)r * N + n0 + tx*8]     = o0;
      *(float4*)&out[(size_t)r * N + n0 + tx*8 + 4] = o1;
    }
  } else {
    float attv[8];
    #pragma unroll
    for (int j = 0; j < 8; ++j) attv[j] = attV[n0 + tx*8 + j];
    #pragma unroll
    for (int i = 0; i < 8; ++i) {
      const int r = m0 + ty*8 + i;
      const int b = r / S_LEN;
      const float* dtp = dterm + (size_t)b * 512 + n0 + tx*8;
      float p = 0.f;
      #pragma unroll
      for (int j = 0; j < 8; ++j) p += attv[j] * tanhf(acc[i][j] + dtp[j]);
      pr[ty*8+i][tx] = p;
    }
    __syncthreads();
    if (tid < 128) {
      float s = 0.f;
      #pragma unroll
      for (int x = 0; x < 16; ++x) s += pr[tid][x];
      e_part[(size_t)(m0 + tid) * 4 + blockIdx.x] = s;
    }
  }
}

// --------------------------- small kernels ---------------------------------
__global__ __launch_bounds__(128) void k_state(const float* __restrict__ enc,
    const float* __restrict__ red_W, const float* __restrict__ red_b,
    float* __restrict__ state)
{
  const int b = blockIdx.y;
  const int j = blockIdx.x*128 + threadIdx.x;
  float acc = red_b[j];
  const float* fw = enc + ((size_t)b*S_LEN + (S_LEN-1))*1024;
  const float* bw = enc + ((size_t)b*S_LEN + 0)*1024 + 512;
  #pragma unroll 4
  for (int k = 0; k < 512; ++k) acc += fw[k] * red_W[(size_t)k*512 + j];
  #pragma unroll 4
  for (int k = 0; k < 512; ++k) acc += bw[k] * red_W[(size_t)(512+k)*512 + j];
  state[(size_t)b*512 + j] = fmaxf(acc, 0.f);
}

__global__ void k_yemb(const int* __restrict__ y_id, const float* __restrict__ emb,
                       float* __restrict__ yemb)
{
  const int b = blockIdx.x, tid = threadIdx.x;
  const int r = y_id[b];
  yemb[(size_t)b*512 + tid]       = emb[(size_t)r*512 + tid];
  yemb[(size_t)b*512 + 256 + tid] = emb[(size_t)r*512 + 256 + tid];
}

__global__ __launch_bounds__(128) void k_dec(const float* __restrict__ yemb,
    const float* __restrict__ state, const float* __restrict__ dec_W,
    const float* __restrict__ dec_U, const float* __restrict__ dec_b,
    float* __restrict__ dst)
{
  const int b = blockIdx.y;
  const int j = blockIdx.x*128 + threadIdx.x;
  float xz0 = dec_b[j], xz1 = dec_b[512+j], xz2 = dec_b[1024+j];
  float rc0 = dec_b[G3+j], rc1 = dec_b[G3+512+j], rc2 = dec_b[G3+1024+j];
  const float* ye = yemb + (size_t)b*512;
  const float* st = state + (size_t)b*512;
  #pragma unroll 2
  for (int k = 0; k < 512; ++k) {
    const float* wp = dec_W + (size_t)k*G3 + j;
    const float* up = dec_U + (size_t)k*G3 + j;
    const float yv = ye[k], sv = st[k];
    xz0 += yv*wp[0]; xz1 += yv*wp[512]; xz2 += yv*wp[1024];
    rc0 += sv*up[0]; rc1 += sv*up[512]; rc2 += sv*up[1024];
  }
  const float z  = sigf(xz0 + rc0);
  const float r  = sigf(xz1 + rc1);
  const float hh = tanhf(xz2 + r*rc2);
  dst[(size_t)b*512 + j] = z*st[j] + (1.f-z)*hh;
}

__global__ __launch_bounds__(128) void k_dterm(const float* __restrict__ dec,
    const float* __restrict__ att_Ws, const float* __restrict__ att_bs,
    float* __restrict__ dterm)
{
  const int b = blockIdx.y;
  const int j = blockIdx.x*128 + threadIdx.x;
  float acc = att_bs[j];
  const float* d = dec + (size_t)b*512;
  #pragma unroll 4
  for (int k = 0; k < 512; ++k) acc += d[k] * att_Ws[(size_t)k*512 + j];
  dterm[(size_t)b*512 + j] = acc;
}

__global__ __launch_bounds__(512) void k_soft(const float* __restrict__ e_part,
    const int* __restrict__ x_mask, float* __restrict__ wat)
{
  const int b = blockIdx.x, tid = threadIdx.x;
  __shared__ float sm[512];
  float e = -1e30f, ev = 0.f;
  if (tid < S_LEN) {
    const float* ep = e_part + (size_t)(b*S_LEN + tid)*4;
    ev = ep[0]+ep[1]+ep[2]+ep[3] + (float)x_mask[b*S_LEN+tid] * -1e10f;
    e = ev;
  }
  sm[tid] = e; __syncthreads();
  for (int s = 256; s > 0; s >>= 1) { if (tid < s) sm[tid] = fmaxf(sm[tid], sm[tid+s]); __syncthreads(); }
  const float m = sm[0]; __syncthreads();
  const float x = (tid < S_LEN) ? expf(ev - m) : 0.f;
  sm[tid] = x; __syncthreads();
  for (int s = 256; s > 0; s >>= 1) { if (tid < s) sm[tid] += sm[tid+s]; __syncthreads(); }
  const float inv = 1.f / sm[0];
  if (tid < S_LEN) wat[b*S_LEN+tid] = x * inv;
}

__global__ __launch_bounds__(128) void k_ctx(const float* __restrict__ wat,
    const float* __restrict__ enc, float* __restrict__ ctx)
{
  const int b = blockIdx.y;
  const int j = blockIdx.x*128 + threadIdx.x;
  float acc = 0.f;
  const float* w = wat + b*S_LEN;
  const float* ep = enc + (size_t)b*S_LEN*1024 + j;
  #pragma unroll 4
  for (int s = 0; s < S_LEN; ++s) acc += w[s] * ep[(size_t)s*1024];
  ctx[(size_t)b*1024 + j] = acc;
}

__global__ __launch_bounds__(128) void k_yout(const float* __restrict__ dec,
    const float* __restrict__ ctx, const float* __restrict__ fc_W,
    const float* __restrict__ fc_b, float* __restrict__ y_out)
{
  const int b = blockIdx.y;
  const int j = blockIdx.x*128 + threadIdx.x;
  float acc = fc_b[j];
  const float* d = dec + (size_t)b*512;
  const float* c = ctx + (size_t)b*1024;
  #pragma unroll 4
  for (int k = 0; k < 512; ++k)  acc += d[k]*fc_W[(size_t)k*512 + j];
  #pragma unroll 4
  for (int k = 0; k < 1024; ++k) acc += c[k]*fc_W[(size_t)(512+k)*512 + j];
  y_out[(size_t)b*512 + j] = acc;
}

__global__ __launch_bounds__(256) void k_pgen(const float* __restrict__ ctx,
    const float* __restrict__ dec, const float* __restrict__ yemb,
    const float* __restrict__ pg_Wh, const float* __restrict__ pg_Ws,
    const float* __restrict__ pg_Wx, const float* __restrict__ pg_b,
    float* __restrict__ pg)
{
  const int b = blockIdx.x, tid = threadIdx.x;
  __shared__ float sm[256];
  float acc = 0.f;
  for (int k = tid; k < 1024; k += 256) acc += ctx[(size_t)b*1024+k]*pg_Wh[k];
  for (int k = tid; k < 512;  k += 256) acc += dec[(size_t)b*512+k]*pg_Ws[k] + yemb[(size_t)b*512+k]*pg_Wx[k];
  sm[tid] = acc; __syncthreads();
  for (int s = 128; s > 0; s >>= 1) { if (tid < s) sm[tid] += sm[tid+s]; __syncthreads(); }
  if (tid == 0) pg[b] = sigf(sm[0] + pg_b[0]);
}

__global__ __launch_bounds__(256) void k_vocab(const float* __restrict__ y_out,
    const float* __restrict__ vocab_W, float* __restrict__ logits)
{
  __shared__ float y_lds[256][32];   // [k][b], one k-half at a time (32 KB)
  const int tid = threadIdx.x;
  const int vq = tid & 63, bq = tid >> 6;
  const int v = blockIdx.x * 256 + vq * 4;
  float acc[8][4];
  #pragma unroll
  for (int i = 0; i < 8; ++i)
    #pragma unroll
    for (int j = 0; j < 4; ++j) acc[i][j] = 0.f;
  for (int half = 0; half < 2; ++half) {
    __syncthreads();
    for (int i = 0; i < 32; ++i) {
      const int idx = tid + 256*i;
      const int k = idx >> 5, b = idx & 31;
      y_lds[k][b] = y_out[(size_t)b*512 + half*256 + k];
    }
    __syncthreads();
    if (v < VOC) {
      #pragma unroll 4
      for (int k = 0; k < 256; ++k) {
        const float4 wv = *(const float4*)&vocab_W[(size_t)(half*256 + k) * VOC + v];
        const float4 ya = *(const float4*)&y_lds[k][bq*8];
        const float4 yb = *(const float4*)&y_lds[k][bq*8+4];
        const float yy[8] = {ya.x,ya.y,ya.z,ya.w,yb.x,yb.y,yb.z,yb.w};
        #pragma unroll
        for (int i = 0; i < 8; ++i) {
          acc[i][0] += yy[i]*wv.x; acc[i][1] += yy[i]*wv.y;
          acc[i][2] += yy[i]*wv.z; acc[i][3] += yy[i]*wv.w;
        }
      }
    }
  }
  if (v < VOC) {
    #pragma unroll
    for (int i = 0; i < 8; ++i)
      *(float4*)&logits[(size_t)(bq*8+i)*VOC + v] = make_float4(acc[i][0],acc[i][1],acc[i][2],acc[i][3]);
  }
}

__global__ __launch_bounds__(1024) void k_vred(const float* __restrict__ logits,
                                               float* __restrict__ red2)
{
  const int b = blockIdx.x, tid = threadIdx.x;
  __shared__ float sm[1024];
  float m = -1e30f;
  for (int i = tid; i < VOC; i += 1024) m = fmaxf(m, logits[(size_t)b*VOC + i]);
  sm[tid] = m; __syncthreads();
  for (int s = 512; s > 0; s >>= 1) { if (tid < s) sm[tid] = fmaxf(sm[tid], sm[tid+s]); __syncthreads(); }
  m = sm[0]; __syncthreads();
  float sum = 0.f;
  for (int i = tid; i < VOC; i += 1024) sum += expf(logits[(size_t)b*VOC + i] - m);
  sm[tid] = sum; __syncthreads();
  for (int s = 512; s > 0; s >>= 1) { if (tid < s) sm[tid] += sm[tid+s]; __syncthreads(); }
  if (tid == 0) { red2[b*2] = m; red2[b*2+1] = sm[0]; }
}

__global__ __launch_bounds__(256) void k_final(const float* __restrict__ logits,
    const float* __restrict__ red2, const float* __restrict__ pg,
    float* __restrict__ out)
{
  const size_t idx = (size_t)blockIdx.x*256 + threadIdx.x;
  const int b = (int)(idx / OUTW);
  const int c = (int)(idx - (size_t)b*OUTW);
  float v = 0.f;
  if (c < VOC) {
    const float m = red2[b*2], s = red2[b*2+1];
    v = pg[b] * expf(logits[(size_t)b*VOC + c] - m) / s;
  }
  out[idx] = v;
}

__global__ __launch_bounds__(256) void k_scatter(const float* __restrict__ wat,
    const int* __restrict__ x_mask, const float* __restrict__ pg,
    const int* __restrict__ x_id, float* __restrict__ out)
{
  const int i = blockIdx.x*256 + threadIdx.x;   // < 12800
  const int b = i / S_LEN;
  const float aw = wat[i] * (1.f - (float)x_mask[i]) * (1.f - pg[b]);
  atomicAdd(out + (size_t)b*OUTW + x_id[i], aw);
}

// ---------------------------------------------------------------------------
extern "C" void kernel_launch(void* const* d_in, const int* in_sizes, int n_in,
                              void* d_out, int out_size, void* d_ws, size_t ws_size,
                              hipStream_t stream)
{
  (void)in_sizes; (void)n_in; (void)out_size; (void)ws_size;
  const int*   x_id     = (const int*)d_in[0];
  const int*   y_id     = (const int*)d_in[1];
  const int*   x_mask   = (const int*)d_in[2];
  const float* emb      = (const float*)d_in[3];
  const float* enc_fw_W = (const float*)d_in[4];
  const float* enc_fw_U = (const float*)d_in[5];
  const float* enc_fw_b = (const float*)d_in[6];
  const float* enc_bw_W = (const float*)d_in[7];
  const float* enc_bw_U = (const float*)d_in[8];
  const float* enc_bw_b = (const float*)d_in[9];
  const float* red_W    = (const float*)d_in[10];
  const float* red_b    = (const float*)d_in[11];
  const float* dec_W    = (const float*)d_in[12];
  const float* dec_U    = (const float*)d_in[13];
  const float* dec_b    = (const float*)d_in[14];
  const float* att_Wh   = (const float*)d_in[15];
  const float* att_Ws   = (const float*)d_in[16];
  const float* att_bs   = (const float*)d_in[17];
  const float* att_Wc   = (const float*)d_in[18]; (void)att_Wc; // cover == 0
  const float* att_V    = (const float*)d_in[19];
  const float* fc_W     = (const float*)d_in[20];
  const float* fc_b     = (const float*)d_in[21];
  const float* vocab_W  = (const float*)d_in[22];
  const float* pg_Wh    = (const float*)d_in[23];
  const float* pg_Ws    = (const float*)d_in[24];
  const float* pg_Wx    = (const float*)d_in[25];
  const float* pg_b     = (const float*)d_in[26];
  float* out = (float*)d_out;

  float* ws = (float*)d_ws;
  const size_t SZXZ  = (size_t)BATCH*S_LEN*G3;
  const size_t SZENC = (size_t)BATCH*S_LEN*1024;
  float* xzfw   = ws;
  float* xzbw   = xzfw + SZXZ;
  float* enc    = xzbw + SZXZ;
  float* hbuf   = enc + SZENC;
  unsigned* ctr = (unsigned*)(hbuf + 2*2*BATCH*HID);
  float* fstate = (float*)(ctr + 512);
  float* yemb   = fstate + BATCH*HID;
  float* decs   = yemb + BATCH*HID;
  float* dterm  = decs + BATCH*HID;
  float* epart  = dterm + BATCH*HID;
  float* wat    = epart + (size_t)BATCH*S_LEN*4;
  float* ctx    = wat + BATCH*S_LEN;
  float* yout   = ctx + BATCH*1024;
  float* pg     = yout + BATCH*HID;
  float* logits = pg + BATCH;
  float* red2   = logits + (size_t)BATCH*VOC;
  (void)red2;

  hipMemsetAsync(ctr, 0, 512*sizeof(unsigned), stream);

  // input projections xz = gather(emb, x_id) @ W + b[0]
  gemm_big<<<dim3(12,100),256,0,stream>>>(1,0, x_id, emb, 512, enc_fw_W, G3, 512,
                                          enc_fw_b, xzfw, nullptr, nullptr, nullptr);
  gemm_big<<<dim3(12,100),256,0,stream>>>(1,0, x_id, emb, 512, enc_bw_W, G3, 512,
                                          enc_bw_b, xzbw, nullptr, nullptr, nullptr);
  // persistent bidirectional GRU scan
  gru_scan<<<256,256,0,stream>>>(xzfw, xzbw, enc_fw_U, enc_bw_U, enc_fw_b, enc_bw_b,
                                 enc, hbuf, ctr);
  // reduce state + decoder step + attention query term
  k_state<<<dim3(4,32),128,0,stream>>>(enc, red_W, red_b, fstate);
  k_yemb<<<32,256,0,stream>>>(y_id, emb, yemb);
  k_dec<<<dim3(4,32),128,0,stream>>>(yemb, fstate, dec_W, dec_U, dec_b, decs);
  k_dterm<<<dim3(4,32),128,0,stream>>>(decs, att_Ws, att_bs, dterm);
  // attention scores (fused tanh * att_V reduction)
  gemm_big<<<dim3(4,100),256,0,stream>>>(0,1, nullptr, enc, 1024, att_Wh, 512, 1024,
                                         nullptr, nullptr, dterm, att_V, epart);
  k_soft<<<32,512,0,stream>>>(epart, x_mask, wat);
  k_ctx<<<dim3(8,32),128,0,stream>>>(wat, enc, ctx);
  k_yout<<<dim3(4,32),128,0,stream>>>(decs, ctx, fc_W, fc_b, yout);
  k_pgen<<<32,256,0,stream>>>(ctx, decs, yemb, pg_Wh, pg_Ws, pg_Wx, pg_b, pg);
  // vocab distribution + final assembly
  k_vocab<<<196,256,0,stream>>>(yout, vocab_W, logits);
  k_vred<<<32,1024,0,stream>>>(logits, red2);
  k_final<<<6300,256,0,stream>>>(logits, red2, pg, out);
  k_scatter<<<50,256,0,stream>>>(wat, x_mask, pg, x_id, out);
}

// Round 2
// 3686.567 us; speedup vs baseline: 2.2449x; 2.2449x over previous
//
#include <hip/hip_runtime.h>
#include <math.h>

#define S_LEN 400
#define BATCH 32
#define HID   512
#define G3    1536
#define VOC   50000
#define OUTW  (VOC + S_LEN)

typedef unsigned long long ull;

__device__ __forceinline__ float sigf(float x) { return 1.f / (1.f + expf(-x)); }

// ---------------------------------------------------------------------------
// Persistent bidirectional GRU scan, LL-packet synchronization (no barriers).
// grid = 256 blocks x 512 threads. group = bid&7 (dir = group>>2, bg = group&3),
// ht = bid>>3 (16 hidden units per block, full K). Each h element travels as an
// 8-byte {fp32, step-tag} packet through the LLC via relaxed agent atomics.
// hpkt is zeroed before launch => step-0 packets (value 0, tag 0) pre-exist.
// ---------------------------------------------------------------------------
__global__ __launch_bounds__(512) void gru_scan(
    const float* __restrict__ xz_fw, const float* __restrict__ xz_bw,
    const float* __restrict__ Ufw, const float* __restrict__ Ubw,
    const float* __restrict__ bfw, const float* __restrict__ bbw,
    float* __restrict__ enc_seq, ull* __restrict__ hpkt)
{
  const int bid = blockIdx.x;
  const int group = bid & 7;
  const int dir = group >> 2;
  const int bg  = group & 3;
  const int ht  = bid >> 3;          // 0..31, 16 j's each
  const int tid = threadIdx.x;
  const int jl = tid & 15;
  const int kc = tid >> 4;           // 0..31 chunks of 16 k
  const int k0 = kc * 16;
  const int jg = ht * 16 + jl;
  const int w  = tid >> 6;           // wave 0..7

  const float* __restrict__ xz = dir ? xz_bw : xz_fw;
  const float* __restrict__ U  = dir ? Ubw  : Ufw;
  const float* __restrict__ br = (dir ? bbw : bfw) + G3;   // bias row 1

  // U tile in registers: u*[i] = U[k0+i][gate*512 + jg]
  float u0[16], u1[16], u2[16];
  #pragma unroll
  for (int i = 0; i < 16; ++i) {
    const float* up = U + (size_t)(k0 + i) * G3 + jg;
    u0[i] = up[0]; u1[i] = up[512]; u2[i] = up[1024];
  }

  __shared__ float h_lds[8][HID];        // 16 KB
  __shared__ float red[8][3][8][16];     // 12 KB (b, gate, wave, j)

  // consumer mapping: 4096 packets (8 b x 512 j), 8 per thread
  const int cb = tid >> 6;               // batch within group
  const int cj = (tid & 63) * 8;
  // gate/producer mapping (threads 0..127)
  const int gbi = tid >> 4;
  const int gj  = tid & 15;
  const int gjq = ht * 16 + gj;
  const int gb  = bg * 8 + gbi;
  const float brz = br[gjq], brr = br[512 + gjq], brh = br[1024 + gjq];

  ull* __restrict__ pk = hpkt + (size_t)dir * (2 * BATCH * HID);   // [buf][b][j]

  for (int t = 0; t < S_LEN; ++t) {
    const int ts = dir ? (S_LEN - 1 - t) : t;

    // prefetch xz early (independent of h) to hide HBM/L2 latency
    float xzv0 = 0.f, xzv1 = 0.f, xzv2 = 0.f;
    if (tid < 128) {
      const float* xp = xz + ((size_t)gb * S_LEN + ts) * G3 + gjq;
      xzv0 = xp[0]; xzv1 = xp[512]; xzv2 = xp[1024];
    }

    // ---- consume h(t): poll LL packets, fill LDS ----
    {
      ull* base = pk + ((size_t)(t & 1) * BATCH + (bg * 8 + cb)) * HID + cj;
      ull v[8];
      bool ok;
      do {
        ok = true;
        #pragma unroll
        for (int i = 0; i < 8; ++i)
          v[i] = __hip_atomic_load(base + i, __ATOMIC_RELAXED, __HIP_MEMORY_SCOPE_AGENT);
        #pragma unroll
        for (int i = 0; i < 8; ++i)
          ok &= ((unsigned)(v[i] >> 32) == (unsigned)t);
      } while (!ok);
      #pragma unroll
      for (int i = 0; i < 8; ++i)
        h_lds[cb][cj + i] = __uint_as_float((unsigned)v[i]);
    }
    __syncthreads();

    // ---- recurrent matvec: partials over this thread's 16-k chunk ----
    #pragma unroll 1
    for (int b = 0; b < 8; ++b) {
      float a0 = 0.f, a1 = 0.f, a2 = 0.f;
      const float4* hp = (const float4*)&h_lds[b][k0];
      #pragma unroll
      for (int q = 0; q < 4; ++q) {
        const float4 hv = hp[q];
        a0 += hv.x * u0[4*q+0]; a1 += hv.x * u1[4*q+0]; a2 += hv.x * u2[4*q+0];
        a0 += hv.y * u0[4*q+1]; a1 += hv.y * u1[4*q+1]; a2 += hv.y * u2[4*q+1];
        a0 += hv.z * u0[4*q+2]; a1 += hv.z * u1[4*q+2]; a2 += hv.z * u2[4*q+2];
        a0 += hv.w * u0[4*q+3]; a1 += hv.w * u1[4*q+3]; a2 += hv.w * u2[4*q+3];
      }
      // reduce the 4 k-chunks sharing this wave (lanes xor 16, 32)
      a0 += __shfl_xor(a0, 16); a0 += __shfl_xor(a0, 32);
      a1 += __shfl_xor(a1, 16); a1 += __shfl_xor(a1, 32);
      a2 += __shfl_xor(a2, 16); a2 += __shfl_xor(a2, 32);
      if ((tid & 48) == 0) {
        red[b][0][w][jl] = a0;
        red[b][1][w][jl] = a1;
        red[b][2][w][jl] = a2;
      }
    }
    __syncthreads();

    // ---- gates + produce h(t+1) as LL packets ----
    if (tid < 128) {
      float rz = brz, rr = brr, rh = brh;
      #pragma unroll
      for (int x = 0; x < 8; ++x) {
        rz += red[gbi][0][x][gj];
        rr += red[gbi][1][x][gj];
        rh += red[gbi][2][x][gj];
      }
      const float z  = sigf(xzv0 + rz);
      const float r  = sigf(xzv1 + rr);
      const float hh = tanhf(xzv2 + r * rh);
      const float hold = h_lds[gbi][gjq];
      const float hnew = z * hold + (1.f - z) * hh;
      const ull pack = ((ull)(unsigned)(t + 1) << 32) | (ull)__float_as_uint(hnew);
      __hip_atomic_store(pk + ((size_t)((t + 1) & 1) * BATCH + gb) * HID + gjq,
                         pack, __ATOMIC_RELAXED, __HIP_MEMORY_SCOPE_AGENT);
      enc_seq[((size_t)gb * S_LEN + ts) * 1024 + dir * 512 + gjq] = hnew;
    }
    __syncthreads();   // protect h_lds/red before next iteration refills
  }
}

// ---------------------------------------------------------------------------
// fp32 tiled GEMM, 128x128x16, 256 thr, 8x8 microtile.
// gather: A row = emb[rowids[r]] (embedding gather fused).
// epi_att: fused tanh(acc + dterm) * att_V row-reduction -> e_part.
// ---------------------------------------------------------------------------
__global__ __launch_bounds__(256) void gemm_big(
    const int gather, const int epi_att,
    const int* __restrict__ rowids,
    const float* __restrict__ Abase, const int lda,
    const float* __restrict__ W, const int N, const int K,
    const float* __restrict__ bias,
    float* __restrict__ out,
    const float* __restrict__ dterm, const float* __restrict__ attV,
    float* __restrict__ e_part)
{
  const int m0 = blockIdx.y * 128, n0 = blockIdx.x * 128;
  const int tid = threadIdx.x;
  __shared__ float As[16][128];
  __shared__ float Bs[16][128];
  __shared__ int   rid[128];
  __shared__ float pr[128][16];
  if (tid < 128) rid[tid] = gather ? rowids[m0 + tid] : (m0 + tid);
  __syncthreads();
  float acc[8][8];
  #pragma unroll
  for (int i = 0; i < 8; ++i)
    #pragma unroll
    for (int j = 0; j < 8; ++j) acc[i][j] = 0.f;
  const int tx = tid & 15, ty = tid >> 4;
  const int ar = tid >> 1, ac = (tid & 1) * 8;
  const int bc = tid >> 4, bn = (tid & 15) * 8;

  for (int k0 = 0; k0 < K; k0 += 16) {
    const float* ap = Abase + (size_t)rid[ar] * lda + k0 + ac;
    const float4 av0 = *(const float4*)ap;
    const float4 av1 = *(const float4*)(ap + 4);
    const float* bp = W + (size_t)(k0 + bc) * N + n0 + bn;
    const float4 bv0 = *(const float4*)bp;
    const float4 bv1 = *(const float4*)(bp + 4);
    As[ac+0][ar] = av0.x; As[ac+1][ar] = av0.y; As[ac+2][ar] = av0.z; As[ac+3][ar] = av0.w;
    As[ac+4][ar] = av1.x; As[ac+5][ar] = av1.y; As[ac+6][ar] = av1.z; As[ac+7][ar] = av1.w;
    *(float4*)&Bs[bc][bn]   = bv0;
    *(float4*)&Bs[bc][bn+4] = bv1;
    __syncthreads();
    #pragma unroll
    for (int kk = 0; kk < 16; ++kk) {
      const float4 a0 = *(const float4*)&As[kk][ty*8];
      const float4 a1 = *(const float4*)&As[kk][ty*8+4];
      const float4 b0 = *(const float4*)&Bs[kk][tx*8];
      const float4 b1 = *(const float4*)&Bs[kk][tx*8+4];
      const float a[8]  = {a0.x,a0.y,a0.z,a0.w,a1.x,a1.y,a1.z,a1.w};
      const float bb[8] = {b0.x,b0.y,b0.z,b0.w,b1.x,b1.y,b1.z,b1.w};
      #pragma unroll
      for (int i = 0; i < 8; ++i)
        #pragma unroll
        for (int j = 0; j < 8; ++j)
          acc[i][j] += a[i] * bb[j];
    }
    __syncthreads();
  }

  if (!epi_att) {
    #pragma unroll
    for (int i = 0; i < 8; ++i) {
      const int r = m0 + ty*8 + i;
      float4 o0, o1;
      o0.x = acc[i][0] + bias[n0+tx*8+0];
      o0.y = acc[i][1] + bias[n0+tx*8+1];
      o0.z = acc[i][2] + bias[n0+tx*8+2];
      o0.w = acc[i][3] + bias[n0+tx*8+3];
      o1.x = acc[i][4] + bias[n0+tx*8+4];
      o1.y = acc[i][5] + bias[n0+tx*8+5];
      o1.z = acc[i][6] + bias[n0+tx*8+6];
      o1.w = acc[i][7] + bias[n0+tx*8+7];
      *(float4*)&out[(size_t)r * N + n0 + tx*8]     = o0;
      *(float4*)&out[(size_t)r * N + n0 + tx*8 + 4] = o1;
    }
  } else {
    float attv[8];
    #pragma unroll
    for (int j = 0; j < 8; ++j) attv[j] = attV[n0 + tx*8 + j];
    #pragma unroll
    for (int i = 0; i < 8; ++i) {
      const int r = m0 + ty*8 + i;
      const int b = r / S_LEN;
      const float* dtp = dterm + (size_t)b * 512 + n0 + tx*8;
      float p = 0.f;
      #pragma unroll
      for (int j = 0; j < 8; ++j) p += attv[j] * tanhf(acc[i][j] + dtp[j]);
      pr[ty*8+i][tx] = p;
    }
    __syncthreads();
    if (tid < 128) {
      float s = 0.f;
      #pragma unroll
      for (int x = 0; x < 16; ++x) s += pr[tid][x];
      e_part[(size_t)(m0 + tid) * 4 + blockIdx.x] = s;
    }
  }
}

// --------------------------- small kernels ---------------------------------
__global__ __launch_bounds__(128) void k_state(const float* __restrict__ enc,
    const float* __restrict__ red_W, const float* __restrict__ red_b,
    float* __restrict__ state)
{
  const int b = blockIdx.y;
  const int j = blockIdx.x*128 + threadIdx.x;
  float acc = red_b[j];
  const float* fw = enc + ((size_t)b*S_LEN + (S_LEN-1))*1024;
  const float* bw = enc + ((size_t)b*S_LEN + 0)*1024 + 512;
  #pragma unroll 4
  for (int k = 0; k < 512; ++k) acc += fw[k] * red_W[(size_t)k*512 + j];
  #pragma unroll 4
  for (int k = 0; k < 512; ++k) acc += bw[k] * red_W[(size_t)(512+k)*512 + j];
  state[(size_t)b*512 + j] = fmaxf(acc, 0.f);
}

__global__ void k_yemb(const int* __restrict__ y_id, const float* __restrict__ emb,
                       float* __restrict__ yemb)
{
  const int b = blockIdx.x, tid = threadIdx.x;
  const int r = y_id[b];
  yemb[(size_t)b*512 + tid]       = emb[(size_t)r*512 + tid];
  yemb[(size_t)b*512 + 256 + tid] = emb[(size_t)r*512 + 256 + tid];
}

__global__ __launch_bounds__(128) void k_dec(const float* __restrict__ yemb,
    const float* __restrict__ state, const float* __restrict__ dec_W,
    const float* __restrict__ dec_U, const float* __restrict__ dec_b,
    float* __restrict__ dst)
{
  const int b = blockIdx.y;
  const int j = blockIdx.x*128 + threadIdx.x;
  float xz0 = dec_b[j], xz1 = dec_b[512+j], xz2 = dec_b[1024+j];
  float rc0 = dec_b[G3+j], rc1 = dec_b[G3+512+j], rc2 = dec_b[G3+1024+j];
  const float* ye = yemb + (size_t)b*512;
  const float* st = state + (size_t)b*512;
  #pragma unroll 2
  for (int k = 0; k < 512; ++k) {
    const float* wp = dec_W + (size_t)k*G3 + j;
    const float* up = dec_U + (size_t)k*G3 + j;
    const float yv = ye[k], sv = st[k];
    xz0 += yv*wp[0]; xz1 += yv*wp[512]; xz2 += yv*wp[1024];
    rc0 += sv*up[0]; rc1 += sv*up[512]; rc2 += sv*up[1024];
  }
  const float z  = sigf(xz0 + rc0);
  const float r  = sigf(xz1 + rc1);
  const float hh = tanhf(xz2 + r*rc2);
  dst[(size_t)b*512 + j] = z*st[j] + (1.f-z)*hh;
}

__global__ __launch_bounds__(128) void k_dterm(const float* __restrict__ dec,
    const float* __restrict__ att_Ws, const float* __restrict__ att_bs,
    float* __restrict__ dterm)
{
  const int b = blockIdx.y;
  const int j = blockIdx.x*128 + threadIdx.x;
  float acc = att_bs[j];
  const float* d = dec + (size_t)b*512;
  #pragma unroll 4
  for (int k = 0; k < 512; ++k) acc += d[k] * att_Ws[(size_t)k*512 + j];
  dterm[(size_t)b*512 + j] = acc;
}

__global__ __launch_bounds__(512) void k_soft(const float* __restrict__ e_part,
    const int* __restrict__ x_mask, float* __restrict__ wat)
{
  const int b = blockIdx.x, tid = threadIdx.x;
  __shared__ float sm[512];
  float e = -1e30f, ev = 0.f;
  if (tid < S_LEN) {
    const float* ep = e_part + (size_t)(b*S_LEN + tid)*4;
    ev = ep[0]+ep[1]+ep[2]+ep[3] + (float)x_mask[b*S_LEN+tid] * -1e10f;
    e = ev;
  }
  sm[tid] = e; __syncthreads();
  for (int s = 256; s > 0; s >>= 1) { if (tid < s) sm[tid] = fmaxf(sm[tid], sm[tid+s]); __syncthreads(); }
  const float m = sm[0]; __syncthreads();
  const float x = (tid < S_LEN) ? expf(ev - m) : 0.f;
  sm[tid] = x; __syncthreads();
  for (int s = 256; s > 0; s >>= 1) { if (tid < s) sm[tid] += sm[tid+s]; __syncthreads(); }
  const float inv = 1.f / sm[0];
  if (tid < S_LEN) wat[b*S_LEN+tid] = x * inv;
}

__global__ __launch_bounds__(128) void k_ctx(const float* __restrict__ wat,
    const float* __restrict__ enc, float* __restrict__ ctx)
{
  const int b = blockIdx.y;
  const int j = blockIdx.x*128 + threadIdx.x;
  float acc = 0.f;
  const float* w = wat + b*S_LEN;
  const float* ep = enc + (size_t)b*S_LEN*1024 + j;
  #pragma unroll 4
  for (int s = 0; s < S_LEN; ++s) acc += w[s] * ep[(size_t)s*1024];
  ctx[(size_t)b*1024 + j] = acc;
}

__global__ __launch_bounds__(128) void k_yout(const float* __restrict__ dec,
    const float* __restrict__ ctx, const float* __restrict__ fc_W,
    const float* __restrict__ fc_b, float* __restrict__ y_out)
{
  const int b = blockIdx.y;
  const int j = blockIdx.x*128 + threadIdx.x;
  float acc = fc_b[j];
  const float* d = dec + (size_t)b*512;
  const float* c = ctx + (size_t)b*1024;
  #pragma unroll 4
  for (int k = 0; k < 512; ++k)  acc += d[k]*fc_W[(size_t)k*512 + j];
  #pragma unroll 4
  for (int k = 0; k < 1024; ++k) acc += c[k]*fc_W[(size_t)(512+k)*512 + j];
  y_out[(size_t)b*512 + j] = acc;
}

__global__ __launch_bounds__(256) void k_pgen(const float* __restrict__ ctx,
    const float* __restrict__ dec, const float* __restrict__ yemb,
    const float* __restrict__ pg_Wh, const float* __restrict__ pg_Ws,
    const float* __restrict__ pg_Wx, const float* __restrict__ pg_b,
    float* __restrict__ pg)
{
  const int b = blockIdx.x, tid = threadIdx.x;
  __shared__ float sm[256];
  float acc = 0.f;
  for (int k = tid; k < 1024; k += 256) acc += ctx[(size_t)b*1024+k]*pg_Wh[k];
  for (int k = tid; k < 512;  k += 256) acc += dec[(size_t)b*512+k]*pg_Ws[k] + yemb[(size_t)b*512+k]*pg_Wx[k];
  sm[tid] = acc; __syncthreads();
  for (int s = 128; s > 0; s >>= 1) { if (tid < s) sm[tid] += sm[tid+s]; __syncthreads(); }
  if (tid == 0) pg[b] = sigf(sm[0] + pg_b[0]);
}

__global__ __launch_bounds__(256) void k_vocab(const float* __restrict__ y_out,
    const float* __restrict__ vocab_W, float* __restrict__ logits)
{
  __shared__ float y_lds[256][32];   // [k][b], one k-half at a time (32 KB)
  const int tid = threadIdx.x;
  const int vq = tid & 63, bq = tid >> 6;
  const int v = blockIdx.x * 256 + vq * 4;
  float acc[8][4];
  #pragma unroll
  for (int i = 0; i < 8; ++i)
    #pragma unroll
    for (int j = 0; j < 4; ++j) acc[i][j] = 0.f;
  for (int half = 0; half < 2; ++half) {
    __syncthreads();
    for (int i = 0; i < 32; ++i) {
      const int idx = tid + 256*i;
      const int k = idx >> 5, b = idx & 31;
      y_lds[k][b] = y_out[(size_t)b*512 + half*256 + k];
    }
    __syncthreads();
    if (v < VOC) {
      #pragma unroll 4
      for (int k = 0; k < 256; ++k) {
        const float4 wv = *(const float4*)&vocab_W[(size_t)(half*256 + k) * VOC + v];
        const float4 ya = *(const float4*)&y_lds[k][bq*8];
        const float4 yb = *(const float4*)&y_lds[k][bq*8+4];
        const float yy[8] = {ya.x,ya.y,ya.z,ya.w,yb.x,yb.y,yb.z,yb.w};
        #pragma unroll
        for (int i = 0; i < 8; ++i) {
          acc[i][0] += yy[i]*wv.x; acc[i][1] += yy[i]*wv.y;
          acc[i][2] += yy[i]*wv.z; acc[i][3] += yy[i]*wv.w;
        }
      }
    }
  }
  if (v < VOC) {
    #pragma unroll
    for (int i = 0; i < 8; ++i)
      *(float4*)&logits[(size_t)(bq*8+i)*VOC + v] = make_float4(acc[i][0],acc[i][1],acc[i][2],acc[i][3]);
  }
}

__global__ __launch_bounds__(1024) void k_vred(const float* __restrict__ logits,
                                               float* __restrict__ red2)
{
  const int b = blockIdx.x, tid = threadIdx.x;
  __shared__ float sm[1024];
  float m = -1e30f;
  for (int i = tid; i < VOC; i += 1024) m = fmaxf(m, logits[(size_t)b*VOC + i]);
  sm[tid] = m; __syncthreads();
  for (int s = 512; s > 0; s >>= 1) { if (tid < s) sm[tid] = fmaxf(sm[tid], sm[tid+s]); __syncthreads(); }
  m = sm[0]; __syncthreads();
  float sum = 0.f;
  for (int i = tid; i < VOC; i += 1024) sum += expf(logits[(size_t)b*VOC + i] - m);
  sm[tid] = sum; __syncthreads();
  for (int s = 512; s > 0; s >>= 1) { if (tid < s) sm[tid] += sm[tid+s]; __syncthreads(); }
  if (tid == 0) { red2[b*2] = m; red2[b*2+1] = sm[0]; }
}

__global__ __launch_bounds__(256) void k_final(const float* __restrict__ logits,
    const float* __restrict__ red2, const float* __restrict__ pg,
    float* __restrict__ out)
{
  const size_t idx = (size_t)blockIdx.x*256 + threadIdx.x;
  const int b = (int)(idx / OUTW);
  const int c = (int)(idx - (size_t)b*OUTW);
  float v = 0.f;
  if (c < VOC) {
    const float m = red2[b*2], s = red2[b*2+1];
    v = pg[b] * expf(logits[(size_t)b*VOC + c] - m) / s;
  }
  out[idx] = v;
}

__global__ __launch_bounds__(256) void k_scatter(const float* __restrict__ wat,
    const int* __restrict__ x_mask, const float* __restrict__ pg,
    const int* __restrict__ x_id, float* __restrict__ out)
{
  const int i = blockIdx.x*256 + threadIdx.x;   // < 12800
  const int b = i / S_LEN;
  const float aw = wat[i] * (1.f - (float)x_mask[i]) * (1.f - pg[b]);
  atomicAdd(out + (size_t)b*OUTW + x_id[i], aw);
}

// ---------------------------------------------------------------------------
extern "C" void kernel_launch(void* const* d_in, const int* in_sizes, int n_in,
                              void* d_out, int out_size, void* d_ws, size_t ws_size,
                              hipStream_t stream)
{
  (void)in_sizes; (void)n_in; (void)out_size; (void)ws_size;
  const int*   x_id     = (const int*)d_in[0];
  const int*   y_id     = (const int*)d_in[1];
  const int*   x_mask   = (const int*)d_in[2];
  const float* emb      = (const float*)d_in[3];
  const float* enc_fw_W = (const float*)d_in[4];
  const float* enc_fw_U = (const float*)d_in[5];
  const float* enc_fw_b = (const float*)d_in[6];
  const float* enc_bw_W = (const float*)d_in[7];
  const float* enc_bw_U = (const float*)d_in[8];
  const float* enc_bw_b = (const float*)d_in[9];
  const float* red_W    = (const float*)d_in[10];
  const float* red_b    = (const float*)d_in[11];
  const float* dec_W    = (const float*)d_in[12];
  const float* dec_U    = (const float*)d_in[13];
  const float* dec_b    = (const float*)d_in[14];
  const float* att_Wh   = (const float*)d_in[15];
  const float* att_Ws   = (const float*)d_in[16];
  const float* att_bs   = (const float*)d_in[17];
  const float* att_Wc   = (const float*)d_in[18]; (void)att_Wc; // cover == 0
  const float* att_V    = (const float*)d_in[19];
  const float* fc_W     = (const float*)d_in[20];
  const float* fc_b     = (const float*)d_in[21];
  const float* vocab_W  = (const float*)d_in[22];
  const float* pg_Wh    = (const float*)d_in[23];
  const float* pg_Ws    = (const float*)d_in[24];
  const float* pg_Wx    = (const float*)d_in[25];
  const float* pg_b     = (const float*)d_in[26];
  float* out = (float*)d_out;

  float* ws = (float*)d_ws;
  const size_t SZXZ  = (size_t)BATCH*S_LEN*G3;
  const size_t SZENC = (size_t)BATCH*S_LEN*1024;
  const size_t NPKT  = (size_t)2*2*BATCH*HID;      // [dir][buf][b][j]
  float* xzfw   = ws;
  float* xzbw   = xzfw + SZXZ;
  float* enc    = xzbw + SZXZ;
  ull*   hpkt   = (ull*)(enc + SZENC);
  float* fstate = (float*)(hpkt + NPKT);
  float* yemb   = fstate + BATCH*HID;
  float* decs   = yemb + BATCH*HID;
  float* dterm  = decs + BATCH*HID;
  float* epart  = dterm + BATCH*HID;
  float* wat    = epart + (size_t)BATCH*S_LEN*4;
  float* ctx    = wat + BATCH*S_LEN;
  float* yout   = ctx + BATCH*1024;
  float* pg     = yout + BATCH*HID;
  float* logits = pg + BATCH;
  float* red2   = logits + (size_t)BATCH*VOC;

  // zero the LL packet buffer: {0.0f, tag 0} == valid h(0) for every slot
  hipMemsetAsync(hpkt, 0, NPKT * sizeof(ull), stream);

  // input projections xz = gather(emb, x_id) @ W + b[0]
  gemm_big<<<dim3(12,100),256,0,stream>>>(1,0, x_id, emb, 512, enc_fw_W, G3, 512,
                                          enc_fw_b, xzfw, nullptr, nullptr, nullptr);
  gemm_big<<<dim3(12,100),256,0,stream>>>(1,0, x_id, emb, 512, enc_bw_W, G3, 512,
                                          enc_bw_b, xzbw, nullptr, nullptr, nullptr);
  // persistent bidirectional GRU scan (LL-packet sync, no barriers)
  gru_scan<<<256,512,0,stream>>>(xzfw, xzbw, enc_fw_U, enc_bw_U, enc_fw_b, enc_bw_b,
                                 enc, hpkt);
  // reduce state + decoder step + attention query term
  k_state<<<dim3(4,32),128,0,stream>>>(enc, red_W, red_b, fstate);
  k_yemb<<<32,256,0,stream>>>(y_id, emb, yemb);
  k_dec<<<dim3(4,32),128,0,stream>>>(yemb, fstate, dec_W, dec_U, dec_b, decs);
  k_dterm<<<dim3(4,32),128,0,stream>>>(decs, att_Ws, att_bs, dterm);
  // attention scores (fused tanh * att_V reduction)
  gemm_big<<<dim3(4,100),256,0,stream>>>(0,1, nullptr, enc, 1024, att_Wh, 512, 1024,
                                         nullptr, nullptr, dterm, att_V, epart);
  k_soft<<<32,512,0,stream>>>(epart, x_mask, wat);
  k_ctx<<<dim3(8,32),128,0,stream>>>(wat, enc, ctx);
  k_yout<<<dim3(4,32),128,0,stream>>>(decs, ctx, fc_W, fc_b, yout);
  k_pgen<<<32,256,0,stream>>>(ctx, decs, yemb, pg_Wh, pg_Ws, pg_Wx, pg_b, pg);
  // vocab distribution + final assembly
  k_vocab<<<196,256,0,stream>>>(yout, vocab_W, logits);
  k_vred<<<32,1024,0,stream>>>(logits, red2);
  k_final<<<6300,256,0,stream>>>(logits, red2, pg, out);
  k_scatter<<<50,256,0,stream>>>(wat, x_mask, pg, x_id, out);
}